// Round 11
// baseline (258.457 us; speedup 1.0000x reference)
//
#include <hip/hip_runtime.h>
#include <hip/hip_bf16.h>
#include <hip/hip_fp16.h>

#define B_    4096
#define ARITY 6
#define EMB   100
#define NF    200
#define FC    1200
#define NROWS (B_*ARITY)      // 24576
#define MPAD  (B_*8)          // 32768 padded M rows (8 per batch, 2 sentinel)
#define NPAD  2560            // N rows of W_h (A/C pairs interleaved; 2400 real + pad)
#define BN_EPS 1e-5f
#define KP    224
#define SENT  32768.0f
#define NTW   (NPAD/8/16)     // 20 tiles of 16 N-rows per wave (o-eighth)

typedef _Float16 half8 __attribute__((ext_vector_type(8)));
typedef float f32x4 __attribute__((ext_vector_type(4)));

// ws float offsets
#define MRAW_OFF 0              // m_raw f16 [24576][200] -> 2,457,600 f
#define WH_OFF   2457600        // W_h f16 [2560][224]    ->   286,720 f (LINEAR)
#define WT_OFF   2744320        // wT  f16 [7][2][224][32] ->   50,176 f (LINEAR)
#define STAT_OFF 2794496        // gshad[16][400]

__device__ __forceinline__ float4 ld4(const float* rr, const float* vr, int e) {
    if (e < EMB)        return *(const float4*)&rr[e];
    else if (e < 2*EMB) return *(const float4*)&vr[e - EMB];
    float4 z = {0.f,0.f,0.f,0.f}; return z;
}

// ---------------- k0: weight prep + out init -------------------------------
// wT (k1): LINEAR [ks][hi|lo][224][32].  W_h (k3): LINEAR rows.
#define K0_W1 (224*28)
#define K0_W2 (K0_W1 + NPAD*28)
#define K0_TOT (K0_W2 + B_)
__launch_bounds__(256)
__global__ void k0_prep(const float* __restrict__ cw, const float* __restrict__ gW,
                        const float* __restrict__ fb,
                        _Float16* __restrict__ wT,
                        _Float16* __restrict__ W_h, float* __restrict__ out)
{
    int id = blockIdx.x * 256 + threadIdx.x;
    if (id < K0_W1) {
        int f = id / 28, s = id - f*28;
        int ks = s >> 2, ls = s & 3;
        int off = ks*14336 + f*32 + ls*8;       // halfs, within hi part
        half8 h, l;
        #pragma unroll
        for (int j = 0; j < 8; ++j) {
            int k = s*8 + j;
            float v = (f < NF && k < NF) ? cw[f*NF + k] : 0.f;
            _Float16 hi = (_Float16)v;
            h[j] = hi; l[j] = (_Float16)(v - (float)hi);
        }
        wT[off]        = h[0];  // placeholder to keep vector stores aligned
        *(half8*)&wT[off] = h;
        *(half8*)&wT[off + 7168] = l;
    } else if (id < K0_W2) {
        int id2 = id - K0_W1;
        int n = id2 / 28, s = id2 - n*28;
        int o = n >> 1, hf = n & 1;
        half8 h;
        #pragma unroll
        for (int j = 0; j < 8; ++j) {
            int k = s*8 + j;
            float v = 0.f;
            if (k < NF && n < 2*FC) v = gW[(size_t)o*400 + hf*200 + k];
            if (k == NF) v = SENT;           // sentinel column
            h[j] = (_Float16)v;
        }
        *(half8*)&W_h[(size_t)n*KP + s*8] = h;
    } else if (id < K0_TOT) {
        out[id - K0_W2] = fb[0];
    }
}

// ---------------- k1: gather + split-f16 MFMA conv + stats -----------------
// Grid 768 (M-tile 32), 4 waves 2Mx2N, WAVE-AUTONOMOUS: A (hi/lo) built once
// in LDS (swizzled) and hoisted to regs; W fragments load DIRECTLY
// global->VGPR from linear wT (28KB/ks slice, L1-hot, shared by all waves).
// No W staging, no barriers, no vmcnt asm. Arithmetic identical to round 10.
// LDS: A hi/lo 28672 | s_sum @28672 | s_sq @29472 | s_ri @30272 | s_vi @30400
__launch_bounds__(256, 4)
__global__ void k1_mfma(const int* __restrict__ x,
                        const float* __restrict__ er,
                        const float* __restrict__ ev,
                        const _Float16* __restrict__ wT,
                        const float* __restrict__ cb,
                        _Float16* __restrict__ m_raw,
                        float* __restrict__ gshad)
{
    __shared__ __align__(16) char smem[30528];
    _Float16* s_ahi = (_Float16*)smem;          // 32x224
    _Float16* s_alo = s_ahi + 7168;
    float* s_sum = (float*)(smem + 28672);
    float* s_sq  = (float*)(smem + 29472);
    int*   s_ri  = (int*)(smem + 30272);
    int*   s_vi  = (int*)(smem + 30400);

    const int t = threadIdx.x, lane = t & 63, wave = t >> 6;
    const int wm = wave >> 1, wn = wave & 1;
    const int R0 = blockIdx.x * 32;
    const int q = lane >> 4, cx = lane & 15;
    const int rdsw = (q ^ ((cx >> 1) & 3)) * 8;

    if (t < 32) {
        int R = R0 + t, b = R / ARITY, a = R - b * ARITY;
        bool is64 = ((x[1] | x[3] | x[5] | x[7]) == 0);
        int base = b * (2*ARITY) + 2*a;
        s_ri[t] = is64 ? x[2*base]     : x[base];
        s_vi[t] = is64 ? x[2*base + 2] : x[base + 1];
    }
    if (t < NF) { s_sum[t] = 0.f; s_sq[t] = 0.f; }
    __syncthreads();

    // ---- build A panel (32 rows x 224, hi+lo), swizzled ----
    for (int c = t; c < 896; c += 256) {
        int row = c / 28, s = c - row*28;
        int key = (row >> 1) & 3;
        int col = (s >> 2)*32 + ((s & 3) ^ key)*8;
        const float* rr = er + (size_t)s_ri[row] * EMB;
        const float* vr = ev + (size_t)s_vi[row] * EMB;
        int e0 = s*8;
        float4 v0 = ld4(rr, vr, e0);
        float4 v1 = ld4(rr, vr, e0 + 4);
        half8 hi, lo;
        hi[0]=(_Float16)v0.x; lo[0]=(_Float16)(v0.x-(float)hi[0]);
        hi[1]=(_Float16)v0.y; lo[1]=(_Float16)(v0.y-(float)hi[1]);
        hi[2]=(_Float16)v0.z; lo[2]=(_Float16)(v0.z-(float)hi[2]);
        hi[3]=(_Float16)v0.w; lo[3]=(_Float16)(v0.w-(float)hi[3]);
        hi[4]=(_Float16)v1.x; lo[4]=(_Float16)(v1.x-(float)hi[4]);
        hi[5]=(_Float16)v1.y; lo[5]=(_Float16)(v1.y-(float)hi[5]);
        hi[6]=(_Float16)v1.z; lo[6]=(_Float16)(v1.z-(float)hi[6]);
        hi[7]=(_Float16)v1.w; lo[7]=(_Float16)(v1.w-(float)hi[7]);
        *(half8*)&s_ahi[row*KP + col] = hi;
        *(half8*)&s_alo[row*KP + col] = lo;
    }
    __syncthreads();

    // ---- hoist A fragments (hi+lo x 7 ks) ----
    f32x4 ah[7], al[7];
    {
        int arow = wm*16 + cx;
        #pragma unroll
        for (int ks = 0; ks < 7; ++ks) {
            ah[ks] = *(const f32x4*)&s_ahi[arow*KP + ks*32 + rdsw];
            al[ks] = *(const f32x4*)&s_alo[arow*KP + ks*32 + rdsw];
        }
    }

    // ---- MFMA: W fragments direct global->VGPR (L1-hot) ----
    f32x4 acc[7];
    #pragma unroll
    for (int nf = 0; nf < 7; ++nf) acc[nf] = (f32x4){0.f,0.f,0.f,0.f};

    #pragma unroll
    for (int ks = 0; ks < 7; ++ks) {
        #pragma unroll
        for (int nf = 0; nf < 7; ++nf) {
            int n = wn*112 + nf*16 + cx;
            const _Float16* wp = wT + ks*14336 + n*32 + q*8;
            f32x4 bh = *(const f32x4*)wp;
            f32x4 bl = *(const f32x4*)(wp + 7168);
            acc[nf] = __builtin_amdgcn_mfma_f32_16x16x32_f16(
                __builtin_bit_cast(half8, ah[ks]),
                __builtin_bit_cast(half8, bh), acc[nf], 0,0,0);
            acc[nf] = __builtin_amdgcn_mfma_f32_16x16x32_f16(
                __builtin_bit_cast(half8, ah[ks]),
                __builtin_bit_cast(half8, bl), acc[nf], 0,0,0);
            acc[nf] = __builtin_amdgcn_mfma_f32_16x16x32_f16(
                __builtin_bit_cast(half8, al[ks]),
                __builtin_bit_cast(half8, bh), acc[nf], 0,0,0);
        }
    }

    // epilogue: +bias, write m_raw (f16), block stats
    #pragma unroll
    for (int nf = 0; nf < 7; ++nf) {
        int f = wn*112 + nf*16 + cx;
        bool valid = (f < NF);
        float bias = valid ? cb[f] : 0.f;
        float ps = 0.f, pq = 0.f;
        #pragma unroll
        for (int reg = 0; reg < 4; ++reg) {
            float vv = acc[nf][reg] + bias;
            if (valid) {
                int R = R0 + wm*16 + q*4 + reg;
                m_raw[(size_t)R*NF + f] = (_Float16)vv;
                ps += vv; pq += vv*vv;
            }
        }
        ps += __shfl_xor(ps, 16); ps += __shfl_xor(ps, 32);
        pq += __shfl_xor(pq, 16); pq += __shfl_xor(pq, 32);
        if (valid && q == 0) { atomicAdd(&s_sum[f], ps); atomicAdd(&s_sq[f], pq); }
    }
    __syncthreads();
    if (t < NF) {
        float* g = gshad + (blockIdx.x & 15) * 400;
        atomicAdd(&g[t], s_sum[t]);
        atomicAdd(&g[t + 200], s_sq[t]);
    }
}

// ---------------- k3: wave-autonomous MFMA, 8 waves, B direct to VGPR ------
// Grid 512 x 512thr (2 blocks/CU = 16 waves/CU = 4/SIMD). Block = 64 padded
// M rows (8 batches); wave owns all 64 rows (av[4][7] regs) x o-EIGHTH
// (320 N-rows = 20 tiles of 16). No barriers in loop; register dbuf bvA/bvB.
// BN finalize inlined. LDS: A 28672 | gbfw2 @28672 (10240) | scsh @38912.
__launch_bounds__(512, 4)
__global__ void k3_mfma(const _Float16* __restrict__ m_raw,
                        const float* __restrict__ gshad,
                        const float* __restrict__ gamma,
                        const float* __restrict__ beta,
                        const _Float16* __restrict__ W_h,
                        const float* __restrict__ gb,
                        const float* __restrict__ fW,
                        float* __restrict__ out)
{
    __shared__ __align__(16) char smem[40704];
    float2* gbfw2 = (float2*)(smem + 28672);
    float*  scsh  = (float*)(smem + 38912);

    const int t = threadIdx.x, lane = t & 63, wave = t >> 6;
    const int q = lane >> 4, cx = lane & 15;
    const int rdsw = (q ^ ((cx >> 1) & 3)) * 8;

    // ---- inlined BN finalize ----
    if (t < 224) {
        float sc = 0.f, sh = 0.f;
        if (t < NF) {
            float s = 0.f, qq = 0.f;
            #pragma unroll
            for (int c = 0; c < 16; ++c) { s += gshad[c*400 + t]; qq += gshad[c*400 + 200 + t]; }
            float inv = 1.0f / (float)NROWS;
            float mu  = s * inv;
            float var = qq * inv - mu*mu;
            float rs  = rsqrtf(var + BN_EPS);
            sc = rs * gamma[t];
            sh = beta[t] - mu*sc;
        }
        scsh[t] = sc; scsh[224 + t] = sh;
    }
    for (int i = t; i < 1280; i += 512) {
        float g = (i < FC) ? gb[i] : 0.f;
        float f = (i < FC) ? fW[i] : 0.f;
        gbfw2[i] = make_float2(g, f);
    }
    __syncthreads();

    // ---- build padded+swizzled A panel (64 rows x 224 f16) ----
    {
        _Float16* sa = (_Float16*)smem;
        for (int c = t; c < 1792; c += 512) {          // 64 rows x 28 chunks
            int Rp = c / 28, s = c - Rp*28;
            int a = Rp & 7, b = Rp >> 3;
            int key = (Rp >> 1) & 3;
            int col = (s >> 2)*32 + ((s & 3) ^ key)*8;
            half8 o;
            #pragma unroll
            for (int j = 0; j < 8; ++j) o[j] = (_Float16)0.f;
            if (a < ARITY && s < 25) {
                int R = (blockIdx.x*8 + b)*ARITY + a;
                half8 in = *(const half8*)&m_raw[(size_t)R*NF + s*8];
                #pragma unroll
                for (int j = 0; j < 8; ++j) {
                    int k = s*8 + j;
                    o[j] = (_Float16)fmaxf((float)in[j]*scsh[k] + scsh[224+k], 0.f);
                }
            } else if (a >= ARITY && s == 25) {
                o[0] = (_Float16)1.0f;                 // k==200 sentinel unit
            }
            *(half8*)&sa[Rp*KP + col] = o;
        }
    }
    __syncthreads();

    // ---- hoist A fragments (4 mf x 7 ks): rows mf*16+cx ----
    f32x4 av[4][7];
    {
        const _Float16* sa = (const _Float16*)smem;
        #pragma unroll
        for (int mf = 0; mf < 4; ++mf) {
            int row = mf*16 + cx;
            #pragma unroll
            for (int ks = 0; ks < 7; ++ks) {
                av[mf][ks] = *(const f32x4*)&sa[row*KP + ks*32 + rdsw];
                asm volatile("" : "+v"(av[mf][ks]));   // force register residency
            }
        }
    }

    // ---- per-wave o-eighth, B direct to regs ----
    const int nbase = wave * (NPAD/8);                 // 320 N-rows per wave
    const char* wsrc = (const char*)(W_h + (size_t)nbase * KP);
    const int boff = cx*448 + q*16;                    // per-lane byte offset

    #define LOADT(BV_, NT_) do {                                             \
        const char* _b = wsrc + (size_t)(NT_)*7168 + boff;                   \
        _Pragma("unroll")                                                    \
        for (int _k = 0; _k < 7; ++_k)                                       \
            BV_[_k] = *(const f32x4*)(_b + _k*64);                           \
    } while (0)

    float preg[4] = {0.f, 0.f, 0.f, 0.f};

    #define TILE(BV_, NT_) do {                                              \
        f32x4 _acc[4];                                                       \
        _Pragma("unroll")                                                    \
        for (int _m = 0; _m < 4; ++_m) _acc[_m] = (f32x4){0.f,0.f,0.f,0.f};  \
        _Pragma("unroll")                                                    \
        for (int _k = 0; _k < 7; ++_k) {                                     \
            _Pragma("unroll")                                                \
            for (int _m = 0; _m < 4; ++_m)                                   \
                _acc[_m] = __builtin_amdgcn_mfma_f32_16x16x32_f16(           \
                    __builtin_bit_cast(half8, av[_m][_k]),                   \
                    __builtin_bit_cast(half8, BV_[_k]), _acc[_m], 0, 0, 0);  \
        }                                                                    \
        _Pragma("unroll")                                                    \
        for (int _m = 0; _m < 4; ++_m) {                                     \
            f32x4 _a4 = _acc[_m];                                            \
            float _v = fminf(fminf(_a4[0], _a4[1]), fminf(_a4[2], _a4[3]));  \
            _v = fminf(_v, __shfl_xor(_v, 16));     /* 8-row batch min */    \
            float _vp = _v + __shfl_xor(_v, 1);     /* A + C halves */       \
            int _o = (nbase + (NT_)*16 + cx) >> 1;                           \
            float2 _gf = gbfw2[_o];                                          \
            float _val = fmaxf(_vp + _gf.x, 0.f) * _gf.y;                    \
            if (((q & 1) == 0) && ((cx & 1) == 0)) preg[_m] += _val;         \
        }                                                                    \
    } while (0)

    f32x4 bvA[7], bvB[7];
    LOADT(bvA, 0);
    for (int nt = 0; nt < NTW; nt += 2) {
        LOADT(bvB, nt + 1);                 // NTW even: nt+1 <= 19 valid
        TILE(bvA, nt);
        if (nt + 2 < NTW) LOADT(bvA, nt + 2);
        TILE(bvB, nt + 1);
    }

    #pragma unroll
    for (int mf = 0; mf < 4; ++mf) {
        float v = preg[mf];
        v += __shfl_xor(v, 2);
        v += __shfl_xor(v, 4);
        v += __shfl_xor(v, 8);
        if (cx == 0 && (q & 1) == 0) {
            int bb = blockIdx.x*8 + mf*2 + (q >> 1);
            atomicAdd(&out[bb], v);
        }
    }
}

extern "C" void kernel_launch(void* const* d_in, const int* in_sizes, int n_in,
                              void* d_out, int out_size, void* d_ws, size_t ws_size,
                              hipStream_t stream)
{
    const int*   x   = (const int*)  d_in[0];
    const float* er  = (const float*)d_in[1];
    const float* ev  = (const float*)d_in[2];
    const float* cw  = (const float*)d_in[3];
    const float* cb  = (const float*)d_in[4];
    const float* gam = (const float*)d_in[5];
    const float* bet = (const float*)d_in[6];
    const float* gW  = (const float*)d_in[7];
    const float* gb  = (const float*)d_in[8];
    const float* fW  = (const float*)d_in[9];
    const float* fb  = (const float*)d_in[10];

    float* ws = (float*)d_ws;
    _Float16* m_raw = (_Float16*)(ws + MRAW_OFF);
    _Float16* W_h   = (_Float16*)(ws + WH_OFF);
    _Float16* wT    = (_Float16*)(ws + WT_OFF);
    float* gshad    = ws + STAT_OFF;
    float* out      = (float*)d_out;

    (void)hipMemsetAsync(gshad, 0, 16*400*sizeof(float), stream);

    k0_prep<<<(K0_TOT + 255)/256, 256, 0, stream>>>(cw, gW, fb, wT, W_h, out);
    k1_mfma<<<NROWS/32, 256, 0, stream>>>(x, er, ev, wT, cb, m_raw, gshad);
    k3_mfma<<<MPAD/64, 512, 0, stream>>>(m_raw, gshad, gam, bet, W_h, gb, fW, out);
}

// Round 12
// 88.447 us; speedup vs baseline: 2.9221x; 2.9221x over previous
//
#include <hip/hip_runtime.h>
#include <hip/hip_bf16.h>
#include <hip/hip_fp16.h>

#define B_    4096
#define ARITY 6
#define EMB   100
#define NF    200
#define FC    1200
#define NROWS (B_*ARITY)      // 24576
#define MPAD  (B_*8)          // 32768 padded M rows (8 per batch, 2 sentinel)
#define NPAD  2432            // N rows of W_h (A/C pairs interleaved)
#define BN_EPS 1e-5f
#define KP    224
#define SENT  32768.0f
#define NTW   (NPAD/4/16)     // 38 tiles of 16 N-rows per wave (o-quarter)

typedef _Float16 half8 __attribute__((ext_vector_type(8)));
typedef float f32x4 __attribute__((ext_vector_type(4)));

// ws float offsets
#define MRAW_OFF 0              // m_raw f16 [24576][200] -> 2,457,600 f
#define WH_OFF   2457600        // W_h f16 [2432][224]    ->   272,384 f (LINEAR)
#define WT_OFF   2729984        // wT  f16 [7][2][224][32] ->   50,176 f (LINEAR)
#define STAT_OFF 2780160        // gshad[16][400]

__device__ __forceinline__ float4 ld4(const float* rr, const float* vr, int e) {
    if (e < EMB)        return *(const float4*)&rr[e];
    else if (e < 2*EMB) return *(const float4*)&vr[e - EMB];
    float4 z = {0.f,0.f,0.f,0.f}; return z;
}

// ---------------- k0: weight prep + out init -------------------------------
// wT (k1): LINEAR [ks][hi|lo][224][32].  W_h (k3): LINEAR rows.
#define K0_W1 (224*28)
#define K0_W2 (K0_W1 + NPAD*28)
#define K0_TOT (K0_W2 + B_)
__launch_bounds__(256)
__global__ void k0_prep(const float* __restrict__ cw, const float* __restrict__ gW,
                        const float* __restrict__ fb,
                        _Float16* __restrict__ wT,
                        _Float16* __restrict__ W_h, float* __restrict__ out)
{
    int id = blockIdx.x * 256 + threadIdx.x;
    if (id < K0_W1) {
        int f = id / 28, s = id - f*28;
        int ks = s >> 2, ls = s & 3;
        int off = ks*14336 + f*32 + ls*8;
        half8 h, l;
        #pragma unroll
        for (int j = 0; j < 8; ++j) {
            int k = s*8 + j;
            float v = (f < NF && k < NF) ? cw[f*NF + k] : 0.f;
            _Float16 hi = (_Float16)v;
            h[j] = hi; l[j] = (_Float16)(v - (float)hi);
        }
        *(half8*)&wT[off] = h;
        *(half8*)&wT[off + 7168] = l;
    } else if (id < K0_W2) {
        int id2 = id - K0_W1;
        int n = id2 / 28, s = id2 - n*28;
        int o = n >> 1, hf = n & 1;
        half8 h;
        #pragma unroll
        for (int j = 0; j < 8; ++j) {
            int k = s*8 + j;
            float v = 0.f;
            if (k < NF && n < 2*FC) v = gW[(size_t)o*400 + hf*200 + k];
            if (k == NF) v = SENT;           // sentinel column
            h[j] = (_Float16)v;
        }
        *(half8*)&W_h[(size_t)n*KP + s*8] = h;
    } else if (id < K0_TOT) {
        out[id - K0_W2] = fb[0];
    }
}

// ---------------- k1: gather + split-f16 MFMA conv + stats -----------------
// Grid 768 (M-tile 32), 4 waves 2Mx2N, wave-autonomous: A (hi/lo) built once
// in LDS (swizzled), hoisted to regs; W fragments direct global->VGPR from
// linear wT (28KB/ks slice, L1/L2-hot). No barriers/vmcnt in the MFMA loop.
__launch_bounds__(256, 3)
__global__ void k1_mfma(const int* __restrict__ x,
                        const float* __restrict__ er,
                        const float* __restrict__ ev,
                        const _Float16* __restrict__ wT,
                        const float* __restrict__ cb,
                        _Float16* __restrict__ m_raw,
                        float* __restrict__ gshad)
{
    __shared__ __align__(16) char smem[30528];
    _Float16* s_ahi = (_Float16*)smem;          // 32x224
    _Float16* s_alo = s_ahi + 7168;
    float* s_sum = (float*)(smem + 28672);
    float* s_sq  = (float*)(smem + 29472);
    int*   s_ri  = (int*)(smem + 30272);
    int*   s_vi  = (int*)(smem + 30400);

    const int t = threadIdx.x, lane = t & 63, wave = t >> 6;
    const int wm = wave >> 1, wn = wave & 1;
    const int R0 = blockIdx.x * 32;
    const int q = lane >> 4, cx = lane & 15;
    const int rdsw = (q ^ ((cx >> 1) & 3)) * 8;

    if (t < 32) {
        int R = R0 + t, b = R / ARITY, a = R - b * ARITY;
        bool is64 = ((x[1] | x[3] | x[5] | x[7]) == 0);
        int base = b * (2*ARITY) + 2*a;
        s_ri[t] = is64 ? x[2*base]     : x[base];
        s_vi[t] = is64 ? x[2*base + 2] : x[base + 1];
    }
    if (t < NF) { s_sum[t] = 0.f; s_sq[t] = 0.f; }
    __syncthreads();

    // ---- build A panel (32 rows x 224, hi+lo), swizzled ----
    for (int c = t; c < 896; c += 256) {
        int row = c / 28, s = c - row*28;
        int key = (row >> 1) & 3;
        int col = (s >> 2)*32 + ((s & 3) ^ key)*8;
        const float* rr = er + (size_t)s_ri[row] * EMB;
        const float* vr = ev + (size_t)s_vi[row] * EMB;
        int e0 = s*8;
        float4 v0 = ld4(rr, vr, e0);
        float4 v1 = ld4(rr, vr, e0 + 4);
        half8 hi, lo;
        hi[0]=(_Float16)v0.x; lo[0]=(_Float16)(v0.x-(float)hi[0]);
        hi[1]=(_Float16)v0.y; lo[1]=(_Float16)(v0.y-(float)hi[1]);
        hi[2]=(_Float16)v0.z; lo[2]=(_Float16)(v0.z-(float)hi[2]);
        hi[3]=(_Float16)v0.w; lo[3]=(_Float16)(v0.w-(float)hi[3]);
        hi[4]=(_Float16)v1.x; lo[4]=(_Float16)(v1.x-(float)hi[4]);
        hi[5]=(_Float16)v1.y; lo[5]=(_Float16)(v1.y-(float)hi[5]);
        hi[6]=(_Float16)v1.z; lo[6]=(_Float16)(v1.z-(float)hi[6]);
        hi[7]=(_Float16)v1.w; lo[7]=(_Float16)(v1.w-(float)hi[7]);
        *(half8*)&s_ahi[row*KP + col] = hi;
        *(half8*)&s_alo[row*KP + col] = lo;
    }
    __syncthreads();

    // ---- hoist A fragments (hi+lo x 7 ks) ----
    f32x4 ah[7], al[7];
    {
        int arow = wm*16 + cx;
        #pragma unroll
        for (int ks = 0; ks < 7; ++ks) {
            ah[ks] = *(const f32x4*)&s_ahi[arow*KP + ks*32 + rdsw];
            al[ks] = *(const f32x4*)&s_alo[arow*KP + ks*32 + rdsw];
        }
    }

    // ---- MFMA: W fragments direct global->VGPR ----
    f32x4 acc[7];
    #pragma unroll
    for (int nf = 0; nf < 7; ++nf) acc[nf] = (f32x4){0.f,0.f,0.f,0.f};

    #pragma unroll
    for (int ks = 0; ks < 7; ++ks) {
        #pragma unroll
        for (int nf = 0; nf < 7; ++nf) {
            int n = wn*112 + nf*16 + cx;
            const _Float16* wp = wT + ks*14336 + n*32 + q*8;
            f32x4 bh = *(const f32x4*)wp;
            f32x4 bl = *(const f32x4*)(wp + 7168);
            acc[nf] = __builtin_amdgcn_mfma_f32_16x16x32_f16(
                __builtin_bit_cast(half8, ah[ks]),
                __builtin_bit_cast(half8, bh), acc[nf], 0,0,0);
            acc[nf] = __builtin_amdgcn_mfma_f32_16x16x32_f16(
                __builtin_bit_cast(half8, ah[ks]),
                __builtin_bit_cast(half8, bl), acc[nf], 0,0,0);
            acc[nf] = __builtin_amdgcn_mfma_f32_16x16x32_f16(
                __builtin_bit_cast(half8, al[ks]),
                __builtin_bit_cast(half8, bh), acc[nf], 0,0,0);
        }
    }

    // epilogue: +bias, write m_raw (f16), block stats
    #pragma unroll
    for (int nf = 0; nf < 7; ++nf) {
        int f = wn*112 + nf*16 + cx;
        bool valid = (f < NF);
        float bias = valid ? cb[f] : 0.f;
        float ps = 0.f, pq = 0.f;
        #pragma unroll
        for (int reg = 0; reg < 4; ++reg) {
            float vv = acc[nf][reg] + bias;
            if (valid) {
                int R = R0 + wm*16 + q*4 + reg;
                m_raw[(size_t)R*NF + f] = (_Float16)vv;
                ps += vv; pq += vv*vv;
            }
        }
        ps += __shfl_xor(ps, 16); ps += __shfl_xor(ps, 32);
        pq += __shfl_xor(pq, 16); pq += __shfl_xor(pq, 32);
        if (valid && q == 0) { atomicAdd(&s_sum[f], ps); atomicAdd(&s_sq[f], pq); }
    }
    __syncthreads();
    if (t < NF) {
        float* g = gshad + (blockIdx.x & 15) * 400;
        atomicAdd(&g[t], s_sum[t]);
        atomicAdd(&g[t + 200], s_sq[t]);
    }
}

// ---------------- k3: wave-autonomous MFMA, triple-buffered B prefetch -----
// Grid 512 x 256thr (round-10 shape: ~240 live VGPR -> 2 waves/SIMD, pinned
// by __launch_bounds__(256,2); round-11 showed 4 waves/SIMD = forced spill).
// Block = 64 padded M rows (8 batches); wave owns all 64 rows (av[4][7]) x
// private o-quarter (608 N-rows = 38 tiles of 16). B direct global->VGPR,
// prefetch distance 2 tiles (bvA/bvB/bvC static ring, unroll-by-3) to cover
// ~400cyc L2 latency. setprio(1) around MFMA cluster (T5: barrier-free
// waves at different phases = the regime where it pays).
// BN finalize inlined. LDS: A 28672 | gbfw2 @28672 (9728) | scsh @38400.
__launch_bounds__(256, 2)
__global__ void k3_mfma(const _Float16* __restrict__ m_raw,
                        const float* __restrict__ gshad,
                        const float* __restrict__ gamma,
                        const float* __restrict__ beta,
                        const _Float16* __restrict__ W_h,
                        const float* __restrict__ gb,
                        const float* __restrict__ fW,
                        float* __restrict__ out)
{
    __shared__ __align__(16) char smem[40192];
    float2* gbfw2 = (float2*)(smem + 28672);
    float*  scsh  = (float*)(smem + 28672 + 9728);

    const int t = threadIdx.x, lane = t & 63, wave = t >> 6;
    const int q = lane >> 4, cx = lane & 15;
    const int rdsw = (q ^ ((cx >> 1) & 3)) * 8;

    // ---- inlined BN finalize ----
    if (t < 224) {
        float sc = 0.f, sh = 0.f;
        if (t < NF) {
            float s = 0.f, qq = 0.f;
            #pragma unroll
            for (int c = 0; c < 16; ++c) { s += gshad[c*400 + t]; qq += gshad[c*400 + 200 + t]; }
            float inv = 1.0f / (float)NROWS;
            float mu  = s * inv;
            float var = qq * inv - mu*mu;
            float rs  = rsqrtf(var + BN_EPS);
            sc = rs * gamma[t];
            sh = beta[t] - mu*sc;
        }
        scsh[t] = sc; scsh[224 + t] = sh;
    }
    for (int i = t; i < 1216; i += 256) {
        float g = (i < FC) ? gb[i] : 0.f;
        float f = (i < FC) ? fW[i] : 0.f;
        gbfw2[i] = make_float2(g, f);
    }
    __syncthreads();

    // ---- build padded+swizzled A panel (64 rows x 224 f16) ----
    {
        _Float16* sa = (_Float16*)smem;
        for (int c = t; c < 1792; c += 256) {          // 64 rows x 28 chunks
            int Rp = c / 28, s = c - Rp*28;
            int a = Rp & 7, b = Rp >> 3;
            int key = (Rp >> 1) & 3;
            int col = (s >> 2)*32 + ((s & 3) ^ key)*8;
            half8 o;
            #pragma unroll
            for (int j = 0; j < 8; ++j) o[j] = (_Float16)0.f;
            if (a < ARITY && s < 25) {
                int R = (blockIdx.x*8 + b)*ARITY + a;
                half8 in = *(const half8*)&m_raw[(size_t)R*NF + s*8];
                #pragma unroll
                for (int j = 0; j < 8; ++j) {
                    int k = s*8 + j;
                    o[j] = (_Float16)fmaxf((float)in[j]*scsh[k] + scsh[224+k], 0.f);
                }
            } else if (a >= ARITY && s == 25) {
                o[0] = (_Float16)1.0f;                 // k==200 sentinel unit
            }
            *(half8*)&sa[Rp*KP + col] = o;
        }
    }
    __syncthreads();

    // ---- hoist A fragments (4 mf x 7 ks): rows mf*16+cx ----
    f32x4 av[4][7];
    {
        const _Float16* sa = (const _Float16*)smem;
        #pragma unroll
        for (int mf = 0; mf < 4; ++mf) {
            int row = mf*16 + cx;
            #pragma unroll
            for (int ks = 0; ks < 7; ++ks) {
                av[mf][ks] = *(const f32x4*)&sa[row*KP + ks*32 + rdsw];
                asm volatile("" : "+v"(av[mf][ks]));   // force register residency
            }
        }
    }

    // ---- per-wave o-quarter, B direct to regs, distance-2 prefetch ----
    const int nbase = wave * (NPAD/4);                 // 608 N-rows per wave
    const char* wsrc = (const char*)(W_h + (size_t)nbase * KP);
    const int boff = cx*448 + q*16;                    // per-lane byte offset

    #define LOADT(BV_, NT_) do {                                             \
        const char* _b = wsrc + (size_t)(NT_)*7168 + boff;                   \
        _Pragma("unroll")                                                    \
        for (int _k = 0; _k < 7; ++_k)                                       \
            BV_[_k] = *(const f32x4*)(_b + _k*64);                           \
    } while (0)

    float preg[4] = {0.f, 0.f, 0.f, 0.f};

    #define TILE(BV_, NT_) do {                                              \
        f32x4 _acc[4];                                                       \
        _Pragma("unroll")                                                    \
        for (int _m = 0; _m < 4; ++_m) _acc[_m] = (f32x4){0.f,0.f,0.f,0.f};  \
        __builtin_amdgcn_s_setprio(1);                                       \
        _Pragma("unroll")                                                    \
        for (int _k = 0; _k < 7; ++_k) {                                     \
            _Pragma("unroll")                                                \
            for (int _m = 0; _m < 4; ++_m)                                   \
                _acc[_m] = __builtin_amdgcn_mfma_f32_16x16x32_f16(           \
                    __builtin_bit_cast(half8, av[_m][_k]),                   \
                    __builtin_bit_cast(half8, BV_[_k]), _acc[_m], 0, 0, 0);  \
        }                                                                    \
        __builtin_amdgcn_s_setprio(0);                                       \
        _Pragma("unroll")                                                    \
        for (int _m = 0; _m < 4; ++_m) {                                     \
            f32x4 _a4 = _acc[_m];                                            \
            float _v = fminf(fminf(_a4[0], _a4[1]), fminf(_a4[2], _a4[3]));  \
            _v = fminf(_v, __shfl_xor(_v, 16));     /* 8-row batch min */    \
            float _vp = _v + __shfl_xor(_v, 1);     /* A + C halves */       \
            int _o = (nbase + (NT_)*16 + cx) >> 1;                           \
            float2 _gf = gbfw2[_o];                                          \
            float _val = fmaxf(_vp + _gf.x, 0.f) * _gf.y;                    \
            if (((q & 1) == 0) && ((cx & 1) == 0)) preg[_m] += _val;         \
        }                                                                    \
    } while (0)

    f32x4 bvA[7], bvB[7], bvC[7];
    LOADT(bvA, 0);
    LOADT(bvB, 1);
    int nt = 0;
    for (; nt + 5 <= NTW; nt += 3) {       // 12 iterations: tiles 0..35
        LOADT(bvC, nt + 2); TILE(bvA, nt);
        LOADT(bvA, nt + 3); TILE(bvB, nt + 1);
        LOADT(bvB, nt + 4); TILE(bvC, nt + 2);
    }
    TILE(bvA, 36);                          // NTW = 38 = 12*3 + 2
    TILE(bvB, 37);

    #pragma unroll
    for (int mf = 0; mf < 4; ++mf) {
        float v = preg[mf];
        v += __shfl_xor(v, 2);
        v += __shfl_xor(v, 4);
        v += __shfl_xor(v, 8);
        if (cx == 0 && (q & 1) == 0) {
            int bb = blockIdx.x*8 + mf*2 + (q >> 1);
            atomicAdd(&out[bb], v);
        }
    }
}

extern "C" void kernel_launch(void* const* d_in, const int* in_sizes, int n_in,
                              void* d_out, int out_size, void* d_ws, size_t ws_size,
                              hipStream_t stream)
{
    const int*   x   = (const int*)  d_in[0];
    const float* er  = (const float*)d_in[1];
    const float* ev  = (const float*)d_in[2];
    const float* cw  = (const float*)d_in[3];
    const float* cb  = (const float*)d_in[4];
    const float* gam = (const float*)d_in[5];
    const float* bet = (const float*)d_in[6];
    const float* gW  = (const float*)d_in[7];
    const float* gb  = (const float*)d_in[8];
    const float* fW  = (const float*)d_in[9];
    const float* fb  = (const float*)d_in[10];

    float* ws = (float*)d_ws;
    _Float16* m_raw = (_Float16*)(ws + MRAW_OFF);
    _Float16* W_h   = (_Float16*)(ws + WH_OFF);
    _Float16* wT    = (_Float16*)(ws + WT_OFF);
    float* gshad    = ws + STAT_OFF;
    float* out      = (float*)d_out;

    (void)hipMemsetAsync(gshad, 0, 16*400*sizeof(float), stream);

    k0_prep<<<(K0_TOT + 255)/256, 256, 0, stream>>>(cw, gW, fb, wT, W_h, out);
    k1_mfma<<<NROWS/32, 256, 0, stream>>>(x, er, ev, wT, cb, m_raw, gshad);
    k3_mfma<<<MPAD/64, 256, 0, stream>>>(m_raw, gshad, gam, bet, W_h, gb, fW, out);
}

// Round 13
// 83.420 us; speedup vs baseline: 3.0982x; 1.0603x over previous
//
#include <hip/hip_runtime.h>
#include <hip/hip_bf16.h>
#include <hip/hip_fp16.h>

#define B_    4096
#define ARITY 6
#define EMB   100
#define NF    200
#define FC    1200
#define NROWS (B_*ARITY)      // 24576
#define MPAD  (B_*8)          // 32768 padded M rows (8 per batch, 2 sentinel)
#define NPAD  2432            // N rows of W_h (A/C pairs interleaved)
#define BN_EPS 1e-5f
#define KP    224
#define SENT  32768.0f
#define NTW   (NPAD/4/16)     // 38 tiles of 16 N-rows per wave (o-quarter)

typedef _Float16 half8 __attribute__((ext_vector_type(8)));
typedef float f32x4 __attribute__((ext_vector_type(4)));

// ws float offsets
#define MRAW_OFF 0              // m_raw f16 [24576][200] -> 2,457,600 f
#define WH_OFF   2457600        // W_h f16, tile-major coalesced -> 272,384 f
#define WT_OFF   2729984        // wT  f16 [ks][hi|lo][14 grp][coalesced] -> 50,176 f
#define STAT_OFF 2780160        // gshad[16][400]

__device__ __forceinline__ float4 ld4(const float* rr, const float* vr, int e) {
    if (e < EMB)        return *(const float4*)&rr[e];
    else if (e < 2*EMB) return *(const float4*)&vr[e - EMB];
    float4 z = {0.f,0.f,0.f,0.f}; return z;
}

// ---------------- k0: weight prep + out init -------------------------------
// COALESCED layouts: a wave-load instruction reads contiguous bytes.
// wT  (k1): half-off = ks*14336 + part*7168 + (f>>4)*512 + (f&15)*32 + q*8
// W_h (k3): half-off = (n>>4)*3584 + ks*512 + (n&15)*32 + q*8
#define K0_W1 (224*28)
#define K0_W2 (K0_W1 + NPAD*28)
#define K0_TOT (K0_W2 + B_)
__launch_bounds__(256)
__global__ void k0_prep(const float* __restrict__ cw, const float* __restrict__ gW,
                        const float* __restrict__ fb,
                        _Float16* __restrict__ wT,
                        _Float16* __restrict__ W_h, float* __restrict__ out)
{
    int id = blockIdx.x * 256 + threadIdx.x;
    if (id < K0_W1) {
        int f = id / 28, s = id - f*28;
        int ks = s >> 2, ls = s & 3;
        int off = ks*14336 + (f >> 4)*512 + (f & 15)*32 + ls*8;
        half8 h, l;
        #pragma unroll
        for (int j = 0; j < 8; ++j) {
            int k = s*8 + j;
            float v = (f < NF && k < NF) ? cw[f*NF + k] : 0.f;
            _Float16 hi = (_Float16)v;
            h[j] = hi; l[j] = (_Float16)(v - (float)hi);
        }
        *(half8*)&wT[off] = h;
        *(half8*)&wT[off + 7168] = l;
    } else if (id < K0_W2) {
        int id2 = id - K0_W1;
        int n = id2 / 28, s = id2 - n*28;
        int o = n >> 1, hf = n & 1;
        int off = (n >> 4)*3584 + (s >> 2)*512 + (n & 15)*32 + (s & 3)*8;
        half8 h;
        #pragma unroll
        for (int j = 0; j < 8; ++j) {
            int k = s*8 + j;
            float v = 0.f;
            if (k < NF && n < 2*FC) v = gW[(size_t)o*400 + hf*200 + k];
            if (k == NF) v = SENT;           // sentinel column
            h[j] = (_Float16)v;
        }
        *(half8*)&W_h[off] = h;
    } else if (id < K0_TOT) {
        out[id - K0_W2] = fb[0];
    }
}

// ---------------- k1: gather + split-f16 MFMA conv + stats -----------------
// Grid 768 (M-tile 32), 4 waves 2Mx2N, wave-autonomous: A (hi/lo) built once
// in LDS (swizzled), hoisted to regs; W fragments direct global->VGPR from
// COALESCED wT (each load instr = 512B contiguous). No barriers in MFMA loop.
__launch_bounds__(256, 3)
__global__ void k1_mfma(const int* __restrict__ x,
                        const float* __restrict__ er,
                        const float* __restrict__ ev,
                        const _Float16* __restrict__ wT,
                        const float* __restrict__ cb,
                        _Float16* __restrict__ m_raw,
                        float* __restrict__ gshad)
{
    __shared__ __align__(16) char smem[30528];
    _Float16* s_ahi = (_Float16*)smem;          // 32x224
    _Float16* s_alo = s_ahi + 7168;
    float* s_sum = (float*)(smem + 28672);
    float* s_sq  = (float*)(smem + 29472);
    int*   s_ri  = (int*)(smem + 30272);
    int*   s_vi  = (int*)(smem + 30400);

    const int t = threadIdx.x, lane = t & 63, wave = t >> 6;
    const int wm = wave >> 1, wn = wave & 1;
    const int R0 = blockIdx.x * 32;
    const int q = lane >> 4, cx = lane & 15;
    const int rdsw = (q ^ ((cx >> 1) & 3)) * 8;

    if (t < 32) {
        int R = R0 + t, b = R / ARITY, a = R - b * ARITY;
        bool is64 = ((x[1] | x[3] | x[5] | x[7]) == 0);
        int base = b * (2*ARITY) + 2*a;
        s_ri[t] = is64 ? x[2*base]     : x[base];
        s_vi[t] = is64 ? x[2*base + 2] : x[base + 1];
    }
    if (t < NF) { s_sum[t] = 0.f; s_sq[t] = 0.f; }
    __syncthreads();

    // ---- build A panel (32 rows x 224, hi+lo), swizzled ----
    for (int c = t; c < 896; c += 256) {
        int row = c / 28, s = c - row*28;
        int key = (row >> 1) & 3;
        int col = (s >> 2)*32 + ((s & 3) ^ key)*8;
        const float* rr = er + (size_t)s_ri[row] * EMB;
        const float* vr = ev + (size_t)s_vi[row] * EMB;
        int e0 = s*8;
        float4 v0 = ld4(rr, vr, e0);
        float4 v1 = ld4(rr, vr, e0 + 4);
        half8 hi, lo;
        hi[0]=(_Float16)v0.x; lo[0]=(_Float16)(v0.x-(float)hi[0]);
        hi[1]=(_Float16)v0.y; lo[1]=(_Float16)(v0.y-(float)hi[1]);
        hi[2]=(_Float16)v0.z; lo[2]=(_Float16)(v0.z-(float)hi[2]);
        hi[3]=(_Float16)v0.w; lo[3]=(_Float16)(v0.w-(float)hi[3]);
        hi[4]=(_Float16)v1.x; lo[4]=(_Float16)(v1.x-(float)hi[4]);
        hi[5]=(_Float16)v1.y; lo[5]=(_Float16)(v1.y-(float)hi[5]);
        hi[6]=(_Float16)v1.z; lo[6]=(_Float16)(v1.z-(float)hi[6]);
        hi[7]=(_Float16)v1.w; lo[7]=(_Float16)(v1.w-(float)hi[7]);
        *(half8*)&s_ahi[row*KP + col] = hi;
        *(half8*)&s_alo[row*KP + col] = lo;
    }
    __syncthreads();

    // ---- hoist A fragments (hi+lo x 7 ks) ----
    f32x4 ah[7], al[7];
    {
        int arow = wm*16 + cx;
        #pragma unroll
        for (int ks = 0; ks < 7; ++ks) {
            ah[ks] = *(const f32x4*)&s_ahi[arow*KP + ks*32 + rdsw];
            al[ks] = *(const f32x4*)&s_alo[arow*KP + ks*32 + rdsw];
        }
    }

    // ---- MFMA: W fragments direct global->VGPR (coalesced 512B/instr) ----
    f32x4 acc[7];
    #pragma unroll
    for (int nf = 0; nf < 7; ++nf) acc[nf] = (f32x4){0.f,0.f,0.f,0.f};

    #pragma unroll
    for (int ks = 0; ks < 7; ++ks) {
        #pragma unroll
        for (int nf = 0; nf < 7; ++nf) {
            const _Float16* wp = wT + ks*14336 + (wn*7 + nf)*512 + cx*32 + q*8;
            f32x4 bh = *(const f32x4*)wp;
            f32x4 bl = *(const f32x4*)(wp + 7168);
            acc[nf] = __builtin_amdgcn_mfma_f32_16x16x32_f16(
                __builtin_bit_cast(half8, ah[ks]),
                __builtin_bit_cast(half8, bh), acc[nf], 0,0,0);
            acc[nf] = __builtin_amdgcn_mfma_f32_16x16x32_f16(
                __builtin_bit_cast(half8, ah[ks]),
                __builtin_bit_cast(half8, bl), acc[nf], 0,0,0);
            acc[nf] = __builtin_amdgcn_mfma_f32_16x16x32_f16(
                __builtin_bit_cast(half8, al[ks]),
                __builtin_bit_cast(half8, bh), acc[nf], 0,0,0);
        }
    }

    // epilogue: +bias, write m_raw (f16), block stats
    #pragma unroll
    for (int nf = 0; nf < 7; ++nf) {
        int f = wn*112 + nf*16 + cx;
        bool valid = (f < NF);
        float bias = valid ? cb[f] : 0.f;
        float ps = 0.f, pq = 0.f;
        #pragma unroll
        for (int reg = 0; reg < 4; ++reg) {
            float vv = acc[nf][reg] + bias;
            if (valid) {
                int R = R0 + wm*16 + q*4 + reg;
                m_raw[(size_t)R*NF + f] = (_Float16)vv;
                ps += vv; pq += vv*vv;
            }
        }
        ps += __shfl_xor(ps, 16); ps += __shfl_xor(ps, 32);
        pq += __shfl_xor(pq, 16); pq += __shfl_xor(pq, 32);
        if (valid && q == 0) { atomicAdd(&s_sum[f], ps); atomicAdd(&s_sq[f], pq); }
    }
    __syncthreads();
    if (t < NF) {
        float* g = gshad + (blockIdx.x & 15) * 400;
        atomicAdd(&g[t], s_sum[t]);
        atomicAdd(&g[t + 200], s_sq[t]);
    }
}

// ---------------- k3: wave-autonomous MFMA, coalesced B, no av pin ---------
// Grid 512 x 256thr, 2 waves/SIMD. Block = 64 padded M rows (8 batches);
// wave owns all 64 rows (av[4][7], AGPR-placed by the allocator — pin
// removed) x private o-quarter (608 N-rows = 38 tiles of 16). B direct
// global->VGPR from COALESCED W_h (each load instr = 1KB contiguous),
// triple-buffer distance-2 prefetch; gbfw2 prefetched 1 tile ahead.
// LDS: A 28672 | gbfw2 @28672 (9728) | scsh @38400.
__launch_bounds__(256, 2)
__global__ void k3_mfma(const _Float16* __restrict__ m_raw,
                        const float* __restrict__ gshad,
                        const float* __restrict__ gamma,
                        const float* __restrict__ beta,
                        const _Float16* __restrict__ W_h,
                        const float* __restrict__ gb,
                        const float* __restrict__ fW,
                        float* __restrict__ out)
{
    __shared__ __align__(16) char smem[40192];
    float2* gbfw2 = (float2*)(smem + 28672);
    float*  scsh  = (float*)(smem + 28672 + 9728);

    const int t = threadIdx.x, lane = t & 63, wave = t >> 6;
    const int q = lane >> 4, cx = lane & 15;
    const int rdsw = (q ^ ((cx >> 1) & 3)) * 8;

    // ---- inlined BN finalize ----
    if (t < 224) {
        float sc = 0.f, sh = 0.f;
        if (t < NF) {
            float s = 0.f, qq = 0.f;
            #pragma unroll
            for (int c = 0; c < 16; ++c) { s += gshad[c*400 + t]; qq += gshad[c*400 + 200 + t]; }
            float inv = 1.0f / (float)NROWS;
            float mu  = s * inv;
            float var = qq * inv - mu*mu;
            float rs  = rsqrtf(var + BN_EPS);
            sc = rs * gamma[t];
            sh = beta[t] - mu*sc;
        }
        scsh[t] = sc; scsh[224 + t] = sh;
    }
    for (int i = t; i < 1216; i += 256) {
        float g = (i < FC) ? gb[i] : 0.f;
        float f = (i < FC) ? fW[i] : 0.f;
        gbfw2[i] = make_float2(g, f);
    }
    __syncthreads();

    // ---- build padded+swizzled A panel (64 rows x 224 f16) ----
    {
        _Float16* sa = (_Float16*)smem;
        for (int c = t; c < 1792; c += 256) {          // 64 rows x 28 chunks
            int Rp = c / 28, s = c - Rp*28;
            int a = Rp & 7, b = Rp >> 3;
            int key = (Rp >> 1) & 3;
            int col = (s >> 2)*32 + ((s & 3) ^ key)*8;
            half8 o;
            #pragma unroll
            for (int j = 0; j < 8; ++j) o[j] = (_Float16)0.f;
            if (a < ARITY && s < 25) {
                int R = (blockIdx.x*8 + b)*ARITY + a;
                half8 in = *(const half8*)&m_raw[(size_t)R*NF + s*8];
                #pragma unroll
                for (int j = 0; j < 8; ++j) {
                    int k = s*8 + j;
                    o[j] = (_Float16)fmaxf((float)in[j]*scsh[k] + scsh[224+k], 0.f);
                }
            } else if (a >= ARITY && s == 25) {
                o[0] = (_Float16)1.0f;                 // k==200 sentinel unit
            }
            *(half8*)&sa[Rp*KP + col] = o;
        }
    }
    __syncthreads();

    // ---- hoist A fragments (4 mf x 7 ks): rows mf*16+cx; no pin (AGPR ok) --
    f32x4 av[4][7];
    {
        const _Float16* sa = (const _Float16*)smem;
        #pragma unroll
        for (int mf = 0; mf < 4; ++mf) {
            int row = mf*16 + cx;
            #pragma unroll
            for (int ks = 0; ks < 7; ++ks)
                av[mf][ks] = *(const f32x4*)&sa[row*KP + ks*32 + rdsw];
        }
    }

    // ---- per-wave o-quarter, coalesced B direct to regs ----
    const int nbase = wave * (NPAD/4);                 // 608 N-rows per wave
    const char* wsrc = (const char*)W_h + (size_t)nbase * 448;  // tile-major
    const int boff = cx*64 + q*16;                     // within-1KB lane offset

    #define LOADT(BV_, GF_, NT_) do {                                        \
        const char* _b = wsrc + (size_t)(NT_)*7168 + boff;                   \
        _Pragma("unroll")                                                    \
        for (int _k = 0; _k < 7; ++_k)                                       \
            BV_[_k] = *(const f32x4*)(_b + _k*1024);                         \
        GF_ = gbfw2[(nbase + (NT_)*16 + cx) >> 1];                           \
    } while (0)

    float preg[4] = {0.f, 0.f, 0.f, 0.f};

    #define TILE(BV_, GF_) do {                                              \
        f32x4 _acc[4];                                                       \
        _Pragma("unroll")                                                    \
        for (int _m = 0; _m < 4; ++_m) _acc[_m] = (f32x4){0.f,0.f,0.f,0.f};  \
        __builtin_amdgcn_s_setprio(1);                                       \
        _Pragma("unroll")                                                    \
        for (int _k = 0; _k < 7; ++_k) {                                     \
            _Pragma("unroll")                                                \
            for (int _m = 0; _m < 4; ++_m)                                   \
                _acc[_m] = __builtin_amdgcn_mfma_f32_16x16x32_f16(           \
                    __builtin_bit_cast(half8, av[_m][_k]),                   \
                    __builtin_bit_cast(half8, BV_[_k]), _acc[_m], 0, 0, 0);  \
        }                                                                    \
        __builtin_amdgcn_s_setprio(0);                                       \
        _Pragma("unroll")                                                    \
        for (int _m = 0; _m < 4; ++_m) {                                     \
            f32x4 _a4 = _acc[_m];                                            \
            float _v = fminf(fminf(_a4[0], _a4[1]), fminf(_a4[2], _a4[3]));  \
            _v = fminf(_v, __shfl_xor(_v, 16));     /* 8-row batch min */    \
            float _vp = _v + __shfl_xor(_v, 1);     /* A + C halves */       \
            float _val = fmaxf(_vp + GF_.x, 0.f) * GF_.y;                    \
            if (((q & 1) == 0) && ((cx & 1) == 0)) preg[_m] += _val;         \
        }                                                                    \
    } while (0)

    f32x4 bvA[7], bvB[7], bvC[7];
    float2 gfA, gfB, gfC;
    LOADT(bvA, gfA, 0);
    LOADT(bvB, gfB, 1);
    int nt = 0;
    for (; nt + 5 <= NTW; nt += 3) {       // 12 iterations: tiles 0..35
        LOADT(bvC, gfC, nt + 2); TILE(bvA, gfA);
        LOADT(bvA, gfA, nt + 3); TILE(bvB, gfB);
        LOADT(bvB, gfB, nt + 4); TILE(bvC, gfC);
    }
    TILE(bvA, gfA);                         // tiles 36, 37 (NTW = 38)
    TILE(bvB, gfB);

    #pragma unroll
    for (int mf = 0; mf < 4; ++mf) {
        float v = preg[mf];
        v += __shfl_xor(v, 2);
        v += __shfl_xor(v, 4);
        v += __shfl_xor(v, 8);
        if (cx == 0 && (q & 1) == 0) {
            int bb = blockIdx.x*8 + mf*2 + (q >> 1);
            atomicAdd(&out[bb], v);
        }
    }
}

extern "C" void kernel_launch(void* const* d_in, const int* in_sizes, int n_in,
                              void* d_out, int out_size, void* d_ws, size_t ws_size,
                              hipStream_t stream)
{
    const int*   x   = (const int*)  d_in[0];
    const float* er  = (const float*)d_in[1];
    const float* ev  = (const float*)d_in[2];
    const float* cw  = (const float*)d_in[3];
    const float* cb  = (const float*)d_in[4];
    const float* gam = (const float*)d_in[5];
    const float* bet = (const float*)d_in[6];
    const float* gW  = (const float*)d_in[7];
    const float* gb  = (const float*)d_in[8];
    const float* fW  = (const float*)d_in[9];
    const float* fb  = (const float*)d_in[10];

    float* ws = (float*)d_ws;
    _Float16* m_raw = (_Float16*)(ws + MRAW_OFF);
    _Float16* W_h   = (_Float16*)(ws + WH_OFF);
    _Float16* wT    = (_Float16*)(ws + WT_OFF);
    float* gshad    = ws + STAT_OFF;
    float* out      = (float*)d_out;

    (void)hipMemsetAsync(gshad, 0, 16*400*sizeof(float), stream);

    k0_prep<<<(K0_TOT + 255)/256, 256, 0, stream>>>(cw, gW, fb, wT, W_h, out);
    k1_mfma<<<NROWS/32, 256, 0, stream>>>(x, er, ev, wT, cb, m_raw, gshad);
    k3_mfma<<<MPAD/64, 256, 0, stream>>>(m_raw, gshad, gam, bet, W_h, gb, fW, out);
}

// Round 14
// 82.655 us; speedup vs baseline: 3.1269x; 1.0093x over previous
//
#include <hip/hip_runtime.h>
#include <hip/hip_bf16.h>
#include <hip/hip_fp16.h>

#define B_    4096
#define ARITY 6
#define EMB   100
#define NF    200
#define FC    1200
#define NROWS (B_*ARITY)      // 24576
#define MPAD  (B_*8)          // 32768 padded M rows (8 per batch, 2 sentinel)
#define NPAD  2432            // N rows of W_h (A/C pairs interleaved)
#define BN_EPS 1e-5f
#define KP    224
#define SENT  32768.0f
#define NTW   (NPAD/4/16)     // 38 tiles of 16 N-rows per wave (o-quarter)

typedef _Float16 half8 __attribute__((ext_vector_type(8)));
typedef float f32x4 __attribute__((ext_vector_type(4)));

// ws float offsets
#define MRAW_OFF 0              // m_raw f16 [24576][200] -> 2,457,600 f
#define WH_OFF   2457600        // W_h f16, tile-major coalesced -> 272,384 f
#define WT_OFF   2729984        // wT  f16 [ks][hi|lo][14 grp][coalesced] -> 50,176 f
#define STAT_OFF 2780160        // gshad[16][400]

__device__ __forceinline__ float4 ld4(const float* rr, const float* vr, int e) {
    if (e < EMB)        return *(const float4*)&rr[e];
    else if (e < 2*EMB) return *(const float4*)&vr[e - EMB];
    float4 z = {0.f,0.f,0.f,0.f}; return z;
}

// ---------------- k0: weight prep + out init -------------------------------
// COALESCED layouts: a wave-load instruction reads contiguous bytes.
// wT  (k1): half-off = ks*14336 + part*7168 + (f>>4)*512 + (f&15)*32 + q*8
// W_h (k3): half-off = (n>>4)*3584 + ks*512 + (n&15)*32 + q*8
#define K0_W1 (224*28)
#define K0_W2 (K0_W1 + NPAD*28)
#define K0_TOT (K0_W2 + B_)
__launch_bounds__(256)
__global__ void k0_prep(const float* __restrict__ cw, const float* __restrict__ gW,
                        const float* __restrict__ fb,
                        _Float16* __restrict__ wT,
                        _Float16* __restrict__ W_h, float* __restrict__ out)
{
    int id = blockIdx.x * 256 + threadIdx.x;
    if (id < K0_W1) {
        int f = id / 28, s = id - f*28;
        int ks = s >> 2, ls = s & 3;
        int off = ks*14336 + (f >> 4)*512 + (f & 15)*32 + ls*8;
        half8 h, l;
        #pragma unroll
        for (int j = 0; j < 8; ++j) {
            int k = s*8 + j;
            float v = (f < NF && k < NF) ? cw[f*NF + k] : 0.f;
            _Float16 hi = (_Float16)v;
            h[j] = hi; l[j] = (_Float16)(v - (float)hi);
        }
        *(half8*)&wT[off] = h;
        *(half8*)&wT[off + 7168] = l;
    } else if (id < K0_W2) {
        int id2 = id - K0_W1;
        int n = id2 / 28, s = id2 - n*28;
        int o = n >> 1, hf = n & 1;
        int off = (n >> 4)*3584 + (s >> 2)*512 + (n & 15)*32 + (s & 3)*8;
        half8 h;
        #pragma unroll
        for (int j = 0; j < 8; ++j) {
            int k = s*8 + j;
            float v = 0.f;
            if (k < NF && n < 2*FC) v = gW[(size_t)o*400 + hf*200 + k];
            if (k == NF) v = SENT;           // sentinel column
            h[j] = (_Float16)v;
        }
        *(half8*)&W_h[off] = h;
    } else if (id < K0_TOT) {
        out[id - K0_W2] = fb[0];
    }
}

// ---------------- k1: gather + split-f16 MFMA conv + stats -----------------
// (unchanged from round 13 -- passing)
__launch_bounds__(256, 3)
__global__ void k1_mfma(const int* __restrict__ x,
                        const float* __restrict__ er,
                        const float* __restrict__ ev,
                        const _Float16* __restrict__ wT,
                        const float* __restrict__ cb,
                        _Float16* __restrict__ m_raw,
                        float* __restrict__ gshad)
{
    __shared__ __align__(16) char smem[30528];
    _Float16* s_ahi = (_Float16*)smem;          // 32x224
    _Float16* s_alo = s_ahi + 7168;
    float* s_sum = (float*)(smem + 28672);
    float* s_sq  = (float*)(smem + 29472);
    int*   s_ri  = (int*)(smem + 30272);
    int*   s_vi  = (int*)(smem + 30400);

    const int t = threadIdx.x, lane = t & 63, wave = t >> 6;
    const int wm = wave >> 1, wn = wave & 1;
    const int R0 = blockIdx.x * 32;
    const int q = lane >> 4, cx = lane & 15;
    const int rdsw = (q ^ ((cx >> 1) & 3)) * 8;

    if (t < 32) {
        int R = R0 + t, b = R / ARITY, a = R - b * ARITY;
        bool is64 = ((x[1] | x[3] | x[5] | x[7]) == 0);
        int base = b * (2*ARITY) + 2*a;
        s_ri[t] = is64 ? x[2*base]     : x[base];
        s_vi[t] = is64 ? x[2*base + 2] : x[base + 1];
    }
    if (t < NF) { s_sum[t] = 0.f; s_sq[t] = 0.f; }
    __syncthreads();

    // ---- build A panel (32 rows x 224, hi+lo), swizzled ----
    for (int c = t; c < 896; c += 256) {
        int row = c / 28, s = c - row*28;
        int key = (row >> 1) & 3;
        int col = (s >> 2)*32 + ((s & 3) ^ key)*8;
        const float* rr = er + (size_t)s_ri[row] * EMB;
        const float* vr = ev + (size_t)s_vi[row] * EMB;
        int e0 = s*8;
        float4 v0 = ld4(rr, vr, e0);
        float4 v1 = ld4(rr, vr, e0 + 4);
        half8 hi, lo;
        hi[0]=(_Float16)v0.x; lo[0]=(_Float16)(v0.x-(float)hi[0]);
        hi[1]=(_Float16)v0.y; lo[1]=(_Float16)(v0.y-(float)hi[1]);
        hi[2]=(_Float16)v0.z; lo[2]=(_Float16)(v0.z-(float)hi[2]);
        hi[3]=(_Float16)v0.w; lo[3]=(_Float16)(v0.w-(float)hi[3]);
        hi[4]=(_Float16)v1.x; lo[4]=(_Float16)(v1.x-(float)hi[4]);
        hi[5]=(_Float16)v1.y; lo[5]=(_Float16)(v1.y-(float)hi[5]);
        hi[6]=(_Float16)v1.z; lo[6]=(_Float16)(v1.z-(float)hi[6]);
        hi[7]=(_Float16)v1.w; lo[7]=(_Float16)(v1.w-(float)hi[7]);
        *(half8*)&s_ahi[row*KP + col] = hi;
        *(half8*)&s_alo[row*KP + col] = lo;
    }
    __syncthreads();

    // ---- hoist A fragments (hi+lo x 7 ks) ----
    f32x4 ah[7], al[7];
    {
        int arow = wm*16 + cx;
        #pragma unroll
        for (int ks = 0; ks < 7; ++ks) {
            ah[ks] = *(const f32x4*)&s_ahi[arow*KP + ks*32 + rdsw];
            al[ks] = *(const f32x4*)&s_alo[arow*KP + ks*32 + rdsw];
        }
    }

    // ---- MFMA: W fragments direct global->VGPR (coalesced 512B/instr) ----
    f32x4 acc[7];
    #pragma unroll
    for (int nf = 0; nf < 7; ++nf) acc[nf] = (f32x4){0.f,0.f,0.f,0.f};

    #pragma unroll
    for (int ks = 0; ks < 7; ++ks) {
        #pragma unroll
        for (int nf = 0; nf < 7; ++nf) {
            const _Float16* wp = wT + ks*14336 + (wn*7 + nf)*512 + cx*32 + q*8;
            f32x4 bh = *(const f32x4*)wp;
            f32x4 bl = *(const f32x4*)(wp + 7168);
            acc[nf] = __builtin_amdgcn_mfma_f32_16x16x32_f16(
                __builtin_bit_cast(half8, ah[ks]),
                __builtin_bit_cast(half8, bh), acc[nf], 0,0,0);
            acc[nf] = __builtin_amdgcn_mfma_f32_16x16x32_f16(
                __builtin_bit_cast(half8, ah[ks]),
                __builtin_bit_cast(half8, bl), acc[nf], 0,0,0);
            acc[nf] = __builtin_amdgcn_mfma_f32_16x16x32_f16(
                __builtin_bit_cast(half8, al[ks]),
                __builtin_bit_cast(half8, bh), acc[nf], 0,0,0);
        }
    }

    // epilogue: +bias, write m_raw (f16), block stats
    #pragma unroll
    for (int nf = 0; nf < 7; ++nf) {
        int f = wn*112 + nf*16 + cx;
        bool valid = (f < NF);
        float bias = valid ? cb[f] : 0.f;
        float ps = 0.f, pq = 0.f;
        #pragma unroll
        for (int reg = 0; reg < 4; ++reg) {
            float vv = acc[nf][reg] + bias;
            if (valid) {
                int R = R0 + wm*16 + q*4 + reg;
                m_raw[(size_t)R*NF + f] = (_Float16)vv;
                ps += vv; pq += vv*vv;
            }
        }
        ps += __shfl_xor(ps, 16); ps += __shfl_xor(ps, 32);
        pq += __shfl_xor(pq, 16); pq += __shfl_xor(pq, 32);
        if (valid && q == 0) { atomicAdd(&s_sum[f], ps); atomicAdd(&s_sq[f], pq); }
    }
    __syncthreads();
    if (t < NF) {
        float* g = gshad + (blockIdx.x & 15) * 400;
        atomicAdd(&g[t], s_sum[t]);
        atomicAdd(&g[t + 200], s_sq[t]);
    }
}

// ---------------- k3: wave-autonomous MFMA, pipelined epilogue -------------
// Grid 512 x 256thr, 2 waves/SIMD. Block = 64 padded M rows; wave owns all
// 64 rows (av[4][7]) x private o-quarter (38 tiles of 16 N-rows). B direct
// global->VGPR, register dbuf; TWO acc banks: step nt = { LOAD(nt+1) ->
// MFMA(nt) -> EPILOGUE(nt-1) }, so the serial shfl-chain of tile nt-1
// schedules under tile nt's MFMAs and nt+1's loads. No setprio (was a
// scheduler fence; measured null). Epilogues run in tile order -> preg
// bit-identical to round 13.
// LDS: A 28672 | gbfw2 @28672 (9728) | scsh @38400.
__launch_bounds__(256, 2)
__global__ void k3_mfma(const _Float16* __restrict__ m_raw,
                        const float* __restrict__ gshad,
                        const float* __restrict__ gamma,
                        const float* __restrict__ beta,
                        const _Float16* __restrict__ W_h,
                        const float* __restrict__ gb,
                        const float* __restrict__ fW,
                        float* __restrict__ out)
{
    __shared__ __align__(16) char smem[40192];
    float2* gbfw2 = (float2*)(smem + 28672);
    float*  scsh  = (float*)(smem + 28672 + 9728);

    const int t = threadIdx.x, lane = t & 63, wave = t >> 6;
    const int q = lane >> 4, cx = lane & 15;
    const int rdsw = (q ^ ((cx >> 1) & 3)) * 8;

    // ---- inlined BN finalize ----
    if (t < 224) {
        float sc = 0.f, sh = 0.f;
        if (t < NF) {
            float s = 0.f, qq = 0.f;
            #pragma unroll
            for (int c = 0; c < 16; ++c) { s += gshad[c*400 + t]; qq += gshad[c*400 + 200 + t]; }
            float inv = 1.0f / (float)NROWS;
            float mu  = s * inv;
            float var = qq * inv - mu*mu;
            float rs  = rsqrtf(var + BN_EPS);
            sc = rs * gamma[t];
            sh = beta[t] - mu*sc;
        }
        scsh[t] = sc; scsh[224 + t] = sh;
    }
    for (int i = t; i < 1216; i += 256) {
        float g = (i < FC) ? gb[i] : 0.f;
        float f = (i < FC) ? fW[i] : 0.f;
        gbfw2[i] = make_float2(g, f);
    }
    __syncthreads();

    // ---- build padded+swizzled A panel (64 rows x 224 f16) ----
    {
        _Float16* sa = (_Float16*)smem;
        for (int c = t; c < 1792; c += 256) {          // 64 rows x 28 chunks
            int Rp = c / 28, s = c - Rp*28;
            int a = Rp & 7, b = Rp >> 3;
            int key = (Rp >> 1) & 3;
            int col = (s >> 2)*32 + ((s & 3) ^ key)*8;
            half8 o;
            #pragma unroll
            for (int j = 0; j < 8; ++j) o[j] = (_Float16)0.f;
            if (a < ARITY && s < 25) {
                int R = (blockIdx.x*8 + b)*ARITY + a;
                half8 in = *(const half8*)&m_raw[(size_t)R*NF + s*8];
                #pragma unroll
                for (int j = 0; j < 8; ++j) {
                    int k = s*8 + j;
                    o[j] = (_Float16)fmaxf((float)in[j]*scsh[k] + scsh[224+k], 0.f);
                }
            } else if (a >= ARITY && s == 25) {
                o[0] = (_Float16)1.0f;                 // k==200 sentinel unit
            }
            *(half8*)&sa[Rp*KP + col] = o;
        }
    }
    __syncthreads();

    // ---- hoist A fragments (4 mf x 7 ks): rows mf*16+cx ----
    f32x4 av[4][7];
    {
        const _Float16* sa = (const _Float16*)smem;
        #pragma unroll
        for (int mf = 0; mf < 4; ++mf) {
            int row = mf*16 + cx;
            #pragma unroll
            for (int ks = 0; ks < 7; ++ks)
                av[mf][ks] = *(const f32x4*)&sa[row*KP + ks*32 + rdsw];
        }
    }

    // ---- per-wave o-quarter, coalesced B direct to regs ----
    const int nbase = wave * (NPAD/4);                 // 608 N-rows per wave
    const char* wsrc = (const char*)W_h + (size_t)nbase * 448;  // tile-major
    const int boff = cx*64 + q*16;                     // within-1KB lane offset

    #define LOADT(BV_, NT_) do {                                             \
        const char* _b = wsrc + (size_t)(NT_)*7168 + boff;                   \
        _Pragma("unroll")                                                    \
        for (int _k = 0; _k < 7; ++_k)                                       \
            BV_[_k] = *(const f32x4*)(_b + _k*1024);                         \
    } while (0)

    #define MFMAT(BV_, ACC_) do {                                            \
        _Pragma("unroll")                                                    \
        for (int _m = 0; _m < 4; ++_m) ACC_[_m] = (f32x4){0.f,0.f,0.f,0.f};  \
        _Pragma("unroll")                                                    \
        for (int _k = 0; _k < 7; ++_k) {                                     \
            _Pragma("unroll")                                                \
            for (int _m = 0; _m < 4; ++_m)                                   \
                ACC_[_m] = __builtin_amdgcn_mfma_f32_16x16x32_f16(           \
                    __builtin_bit_cast(half8, av[_m][_k]),                   \
                    __builtin_bit_cast(half8, BV_[_k]), ACC_[_m], 0, 0, 0);  \
        }                                                                    \
    } while (0)

    float preg[4] = {0.f, 0.f, 0.f, 0.f};

    #define EPI(ACC_, NT_) do {                                              \
        float2 _gf = gbfw2[(nbase + (NT_)*16 + cx) >> 1];                    \
        _Pragma("unroll")                                                    \
        for (int _m = 0; _m < 4; ++_m) {                                     \
            f32x4 _a4 = ACC_[_m];                                            \
            float _v = fminf(fminf(_a4[0], _a4[1]), fminf(_a4[2], _a4[3]));  \
            _v = fminf(_v, __shfl_xor(_v, 16));     /* 8-row batch min */    \
            float _vp = _v + __shfl_xor(_v, 1);     /* A + C halves */       \
            float _val = fmaxf(_vp + _gf.x, 0.f) * _gf.y;                    \
            if (((q & 1) == 0) && ((cx & 1) == 0)) preg[_m] += _val;         \
        }                                                                    \
    } while (0)

    f32x4 bv0[7], bv1[7];
    f32x4 acc0[4], acc1[4];

    LOADT(bv0, 0);
    LOADT(bv1, 1);
    MFMAT(bv0, acc0);                       // tile 0
    // steps nt = 1..34 (17 pairs): LOAD(nt+1) | MFMA(nt) | EPI(nt-1)
    for (int k = 0; k < 17; ++k) {
        int nt = 2*k + 1;
        LOADT(bv0, nt + 1); MFMAT(bv1, acc1); EPI(acc0, nt - 1);
        LOADT(bv1, nt + 2); MFMAT(bv0, acc0); EPI(acc1, nt);
    }
    // tail: nt = 35, 36, 37
    LOADT(bv0, 36); MFMAT(bv1, acc1); EPI(acc0, 34);
    LOADT(bv1, 37); MFMAT(bv0, acc0); EPI(acc1, 35);
    MFMAT(bv1, acc1); EPI(acc0, 36);
    EPI(acc1, 37);

    #pragma unroll
    for (int mf = 0; mf < 4; ++mf) {
        float v = preg[mf];
        v += __shfl_xor(v, 2);
        v += __shfl_xor(v, 4);
        v += __shfl_xor(v, 8);
        if (cx == 0 && (q & 1) == 0) {
            int bb = blockIdx.x*8 + mf*2 + (q >> 1);
            atomicAdd(&out[bb], v);
        }
    }
}

extern "C" void kernel_launch(void* const* d_in, const int* in_sizes, int n_in,
                              void* d_out, int out_size, void* d_ws, size_t ws_size,
                              hipStream_t stream)
{
    const int*   x   = (const int*)  d_in[0];
    const float* er  = (const float*)d_in[1];
    const float* ev  = (const float*)d_in[2];
    const float* cw  = (const float*)d_in[3];
    const float* cb  = (const float*)d_in[4];
    const float* gam = (const float*)d_in[5];
    const float* bet = (const float*)d_in[6];
    const float* gW  = (const float*)d_in[7];
    const float* gb  = (const float*)d_in[8];
    const float* fW  = (const float*)d_in[9];
    const float* fb  = (const float*)d_in[10];

    float* ws = (float*)d_ws;
    _Float16* m_raw = (_Float16*)(ws + MRAW_OFF);
    _Float16* W_h   = (_Float16*)(ws + WH_OFF);
    _Float16* wT    = (_Float16*)(ws + WT_OFF);
    float* gshad    = ws + STAT_OFF;
    float* out      = (float*)d_out;

    (void)hipMemsetAsync(gshad, 0, 16*400*sizeof(float), stream);

    k0_prep<<<(K0_TOT + 255)/256, 256, 0, stream>>>(cw, gW, fb, wT, W_h, out);
    k1_mfma<<<NROWS/32, 256, 0, stream>>>(x, er, ev, wT, cb, m_raw, gshad);
    k3_mfma<<<MPAD/64, 256, 0, stream>>>(m_raw, gshad, gam, bet, W_h, gb, fW, out);
}